// Round 1
// baseline (315.731 us; speedup 1.0000x reference)
//
#include <hip/hip_runtime.h>
#include <math.h>

// Problem geometry (fixed by reference):
//   features: [B=8, C=256, H=64, W=64]  -> HW=4096, NPIX=B*HW=32768, NFEAT=8388608
//   outputs:  [B=8, 2, 256, 256]        -> 524288 pixels, 2 channels each
#define HWPX  4096
#define CCH   256
#define NPIX  32768
#define NCHAN 2048
#define NFEAT 8388608

// Workspace layout (floats):
#define ACC_OFF   0      // [0]=ssq_global [1]=ssq_local [2]=sum_opt_diff
                         // [3]=kl_sum [4]=class1_sum [5]=diff_sum [6]=spatial_sum
                         // [7]=chan_f_sum [8]=chan_att_sum
#define SCHAN_OFF 16     // 2048: per-(b,c) student sums
#define TCHAN_OFF 2064   // 2048: per-(b,c) teacher sums
#define OPTD_OFF  4112   // 32768: opt_diff per pixel
#define HETD_OFF  36880  // 32768: hetero_diff per pixel
#define SSP_OFF   69648  // 32768: student spatial att per pixel
#define TSP_OFF   102416 // 32768: teacher spatial att per pixel
#define ZERO_FLOATS OPTD_OFF   // region to zero each launch

__device__ __forceinline__ float sigmoidf_(float x) { return 1.0f / (1.0f + expf(-x)); }

__device__ __forceinline__ float wred(float v) {
#pragma unroll
  for (int o = 32; o > 0; o >>= 1) v += __shfl_down(v, o, 64);
  return v;
}

// ---------------- Kernel A: one pass over the 5 big feature tensors ----------
// Block: 256 threads = 64 pixels x 4 channel-chunks (wave == chunk, 64 ch each).
__global__ __launch_bounds__(256) void kernA(
    const float* __restrict__ stu, const float* __restrict__ tea,
    const float* __restrict__ o1p, const float* __restrict__ o2p,
    const float* __restrict__ srp, const float* __restrict__ mkp,
    float* __restrict__ ws)
{
  const int tid = threadIdx.x;
  const int pix = tid & 63;     // lane == pixel within block
  const int chunk = tid >> 6;   // wave id == channel chunk
  const int gpix = blockIdx.x * 64 + pix;
  const int b = gpix >> 12;       // / 4096
  const int pin = gpix & 4095;
  const int c0 = chunk * 64;
  int idx = (b * CCH + c0) * HWPX + pin;

  float l2a = 0.f, ca = 0.f, l2b = 0.f, cb = 0.f, ssq = 0.f;
  float s_sum = 0.f, t_sum = 0.f;
  float s_max = -INFINITY, t_max = -INFINITY;

  float* acc   = ws + ACC_OFF;
  float* schan = ws + SCHAN_OFF;
  float* tchan = ws + TCHAN_OFF;

#pragma unroll 4
  for (int i = 0; i < 64; ++i) {
    const float sf = stu[idx];
    const float tf = tea[idx];
    const float o1 = o1p[idx];
    const float o2 = o2p[idx];
    const float sr = srp[idx];
    idx += HWPX;

    float d = o1 - o2;
    l2a += d * d;
    ca  += (o1 * o2) / fmaxf(fabsf(o1) * fabsf(o2), 1e-8f);
    float d2 = o1 - sr;
    l2b += d2 * d2;
    cb  += (o1 * sr) / fmaxf(fabsf(o1) * fabsf(sr), 1e-8f);
    float ds = sf - tf;
    ssq += ds * ds;
    s_sum += sf; t_sum += tf;
    s_max = fmaxf(s_max, sf);
    t_max = fmaxf(t_max, tf);

    // per-(b,c) sums: reduce this channel across the wave's 64 pixels
    float rs = sf, rt = tf;
#pragma unroll
    for (int o = 32; o > 0; o >>= 1) {
      rs += __shfl_down(rs, o, 64);
      rt += __shfl_down(rt, o, 64);
    }
    if (pix == 0) {
      atomicAdd(&schan[b * CCH + c0 + i], rs);
      atomicAdd(&tchan[b * CCH + c0 + i], rt);
    }
  }

  // combine 4 chunks per pixel through LDS (stride 9 words: conflict-free)
  __shared__ float lds[4][64][9];
  {
    float* p = lds[chunk][pix];
    p[0] = l2a; p[1] = ca;  p[2] = l2b; p[3] = cb; p[4] = ssq;
    p[5] = s_sum; p[6] = s_max; p[7] = t_sum; p[8] = t_max;
  }
  __syncthreads();

  if (tid < 64) {  // wave 0: one lane per pixel
    float a0 = 0.f, a1 = 0.f, a2 = 0.f, a3 = 0.f, a4 = 0.f, a5 = 0.f, a7 = 0.f;
    float m6 = -INFINITY, m8 = -INFINITY;
#pragma unroll
    for (int k = 0; k < 4; ++k) {
      const float* q = lds[k][tid];
      a0 += q[0]; a1 += q[1]; a2 += q[2]; a3 += q[3]; a4 += q[4];
      a5 += q[5]; a7 += q[7];
      m6 = fmaxf(m6, q[6]);
      m8 = fmaxf(m8, q[8]);
    }
    const int gp = blockIdx.x * 64 + tid;
    const int bb = gp >> 12;
    const int pp = gp & 4095;

    float l2o = sqrtf(a0 + 1e-6f);
    float opt_d = (l2o + 1.0f - a1 * (1.0f / 256.0f)) * sigmoidf_(l2o * 5.0f);
    float l2h = sqrtf(a2 + 1e-6f);
    float het_d = (l2h + 1.0f - a3 * (1.0f / 256.0f)) * sigmoidf_(l2h * 5.0f);
    float ssp = sigmoidf_(a5 * (1.0f / 256.0f) + m6);
    float tsp = sigmoidf_(a7 * (1.0f / 256.0f) + m8);

    ws[OPTD_OFF + gp] = opt_d;
    ws[HETD_OFF + gp] = het_d;
    ws[SSP_OFF  + gp] = ssp;
    ws[TSP_OFF  + gp] = tsp;

    float mv = mkp[bb * HWPX + pp];
    float r0 = a4;             // sum (s-t)^2 over channels, this pixel
    float r1 = mv * mv * a4;   // masked version
    float r2 = opt_d;          // for mean(opt_diff)
    r0 = wred(r0); r1 = wred(r1); r2 = wred(r2);
    if (tid == 0) {
      atomicAdd(&acc[0], r0);
      atomicAdd(&acc[1], r1);
      atomicAdd(&acc[2], r2);
    }
  }
}

// ---------------- Kernel KL: 2-way softmax KL + class1 MSE -------------------
__global__ __launch_bounds__(256) void kernKL(
    const float* __restrict__ so, const float* __restrict__ to,
    float* __restrict__ ws)
{
  const int gid = blockIdx.x * 256 + threadIdx.x;  // 131072 threads, 4 px each
  const int p4 = gid << 2;
  const int b  = p4 >> 16;       // / 65536 pixels per image
  const int pp = p4 & 65535;
  const int i0 = b * 131072 + pp;  // channel-0 element

  const float4 s0 = *(const float4*)(so + i0);
  const float4 s1 = *(const float4*)(so + i0 + 65536);
  const float4 t0 = *(const float4*)(to + i0);
  const float4 t1 = *(const float4*)(to + i0 + 65536);

  float kl = 0.f, c1 = 0.f;
#define KLC(S0, S1, T0, T1)                                           \
  {                                                                   \
    float xs = (S1 - S0) * 0.25f;                                     \
    float xt = (T1 - T0) * 0.25f;                                     \
    float lzs = fmaxf(xs, 0.f) + log1pf(expf(-fabsf(xs)));            \
    float lzt = fmaxf(xt, 0.f) + log1pf(expf(-fabsf(xt)));            \
    float ls0 = -lzs, ls1 = xs - lzs;                                 \
    float lt0 = -lzt, lt1 = xt - lzt;                                 \
    float pt0 = expf(lt0), pt1 = expf(lt1);                           \
    kl += pt0 * (lt0 - ls0) + pt1 * (lt1 - ls1);                      \
    float ps1 = expf(ls1);                                            \
    float dd = ps1 - pt1;                                             \
    c1 += dd * dd;                                                    \
  }
  KLC(s0.x, s1.x, t0.x, t1.x)
  KLC(s0.y, s1.y, t0.y, t1.y)
  KLC(s0.z, s1.z, t0.z, t1.z)
  KLC(s0.w, s1.w, t0.w, t1.w)
#undef KLC

  kl = wred(kl);
  c1 = wred(c1);
  if ((threadIdx.x & 63) == 0) {
    atomicAdd(&ws[ACC_OFF + 3], kl);
    atomicAdd(&ws[ACC_OFF + 4], c1);
  }
}

// ---------------- Kernel C: mean-dependent terms -----------------------------
__global__ __launch_bounds__(256) void kernC(float* __restrict__ ws)
{
  const int gid = blockIdx.x * 256 + threadIdx.x;  // 0..32767
  float* acc = ws + ACC_OFF;
  const float mean_opt = acc[2] * (1.0f / 32768.0f);
  const float att_w = sigmoidf_(mean_opt * 10.0f);
  const float thr = mean_opt * 1.5f;

  const float od  = ws[OPTD_OFF + gid];
  const float hd  = ws[HETD_OFF + gid];
  const float ssp = ws[SSP_OFF + gid];
  const float tsp = ws[TSP_OFF + gid];
  const float mask = od > thr ? 1.0f : 0.0f;
  const float w = mask * 2.0f + (1.0f - mask) * 0.5f;
  float dt = (hd - od) * w; dt *= dt;
  const float amp = 1.0f + att_w * mask;
  float st = (ssp - tsp) * amp; st *= st;

  float cf = 0.f, catt = 0.f;
  if (gid < NCHAN) {
    const float sm = ws[SCHAN_OFF + gid] * (1.0f / 4096.0f);
    const float tm = ws[TCHAN_OFF + gid] * (1.0f / 4096.0f);
    const float d = sm - tm;
    cf = d * d;
    const float d2 = sigmoidf_(sm) - sigmoidf_(tm);
    catt = d2 * d2;
  }

  dt = wred(dt); st = wred(st); cf = wred(cf); catt = wred(catt);
  if ((threadIdx.x & 63) == 0) {
    atomicAdd(&acc[5], dt);
    atomicAdd(&acc[6], st);
    atomicAdd(&acc[7], cf);
    atomicAdd(&acc[8], catt);
  }
}

// ---------------- Kernel D: final scalar combine -----------------------------
__global__ void kernD(const float* __restrict__ ws, float* __restrict__ out)
{
  if (threadIdx.x != 0 || blockIdx.x != 0) return;
  const float* acc = ws + ACC_OFF;

  const float global_loss = acc[0] * (1.0f / (float)NFEAT);
  const float local_loss  = acc[1] * (1.0f / (float)NFEAT);
  const float chan_f      = acc[7] * (1.0f / (float)NCHAN);
  const float feat = 0.3f * global_loss + 0.5f * local_loss + 0.2f * chan_f;

  const float kl = acc[3] * (16.0f / 8.0f);           // * T^2 / B
  const float c1 = acc[4] * (2.0f / 524288.0f);       // mse * 2 over B*1*HO*HO
  const float outl = kl + c1;

  const float mean_opt = acc[2] * (1.0f / 32768.0f);
  const float att_w = sigmoidf_(mean_opt * 10.0f);
  const float diff_loss = acc[5] * (1.0f / 32768.0f);
  const float spat_loss = acc[6] * (1.0f / 32768.0f);
  const float chan_att  = acc[8] * (1.0f / (float)NCHAN);

  const float alpha = 0.5f * (1.0f + 0.5f * att_w);
  const float beta  = 0.3f * (1.0f - 0.3f * att_w);
  const float gamma = 0.2f * (1.0f + 0.5f * att_w);
  const float datt = alpha * diff_loss + beta * chan_att + gamma * spat_loss;

  const float total = 0.3f * feat + 0.4f * outl + 0.3f * datt;
  out[0] = total;
  out[1] = feat;
  out[2] = outl;
  out[3] = datt;
}

extern "C" void kernel_launch(void* const* d_in, const int* in_sizes, int n_in,
                              void* d_out, int out_size, void* d_ws, size_t ws_size,
                              hipStream_t stream)
{
  const float* stu = (const float*)d_in[0];
  const float* tea = (const float*)d_in[1];
  const float* so  = (const float*)d_in[2];
  const float* to  = (const float*)d_in[3];
  const float* o1  = (const float*)d_in[4];
  const float* o2  = (const float*)d_in[5];
  const float* sr  = (const float*)d_in[6];
  const float* mk  = (const float*)d_in[7];
  float* ws  = (float*)d_ws;
  float* out = (float*)d_out;

  // zero accumulators + chan-sum arrays (ws is poisoned 0xAA each call)
  hipMemsetAsync(d_ws, 0, (size_t)ZERO_FLOATS * sizeof(float), stream);

  kernA<<<NPIX / 64, 256, 0, stream>>>(stu, tea, o1, o2, sr, mk, ws);
  kernKL<<<(524288 / 4) / 256, 256, 0, stream>>>(so, to, ws);
  kernC<<<NPIX / 256, 256, 0, stream>>>(ws);
  kernD<<<1, 64, 0, stream>>>(ws, out);
}

// Round 2
// 300.796 us; speedup vs baseline: 1.0497x; 1.0497x over previous
//
#include <hip/hip_runtime.h>
#include <math.h>

// Problem geometry (fixed by reference):
//   features: [B=8, C=256, H=64, W=64]  -> HW=4096, NPIX=B*HW=32768, NFEAT=8388608
//   outputs:  [B=8, 2, 256, 256]        -> 524288 pixels, 2 channels each
#define HWPX  4096
#define CCH   256
#define NPIX  32768
#define NCHAN 2048
#define NFEAT 8388608

// Workspace layout (floats):
#define ACC_OFF   0      // [0]=ssq_global [1]=ssq_local [2]=sum_opt_diff
                         // [3]=kl_sum [4]=class1_sum [5]=diff_sum [6]=spatial_sum
                         // [7]=chan_f_sum [8]=chan_att_sum
#define SCHAN_OFF 16     // 2048: per-(b,c) student sums (kernB, no atomics)
#define TCHAN_OFF 2064   // 2048: per-(b,c) teacher sums
#define OPTD_OFF  4112   // 32768: opt_diff per pixel
#define HETD_OFF  36880  // 32768: hetero_diff per pixel
#define SSP_OFF   69648  // 32768: student spatial att per pixel
#define TSP_OFF   102416 // 32768: teacher spatial att per pixel

__device__ __forceinline__ float sigmoidf_(float x) { return 1.0f / (1.0f + expf(-x)); }

__device__ __forceinline__ float wred(float v) {
#pragma unroll
  for (int o = 32; o > 0; o >>= 1) v += __shfl_down(v, o, 64);
  return v;
}

// ---------------- Kernel A: streaming pass over the 5 big feature tensors ----
// Block: 256 threads = 4 waves; each wave owns a 64-channel chunk; each lane
// owns 2 consecutive pixels (float2 loads -> 512 B per wave-instruction).
// Block covers 128 pixels x 256 channels. Grid = 32768/128 = 256 blocks.
// NO cross-lane ops in the inner loop (that was the R0 latency killer).
__global__ __launch_bounds__(256) void kernA(
    const float* __restrict__ stu, const float* __restrict__ tea,
    const float* __restrict__ o1p, const float* __restrict__ o2p,
    const float* __restrict__ srp, const float* __restrict__ mkp,
    float* __restrict__ ws)
{
  const int tid   = threadIdx.x;
  const int lane  = tid & 63;
  const int chunk = tid >> 6;                    // channel chunk (0..3)
  const int p0    = blockIdx.x * 128 + lane * 2; // pixel pair (same image: 128 | 4096)
  const int b     = p0 >> 12;
  const int pin   = p0 & 4095;
  const int c0    = chunk * 64;
  size_t idx = ((size_t)(b * CCH + c0)) * HWPX + pin;

  // per-pixel-slot accumulators (x = pixel p0, y = pixel p0+1)
  float l2a_x=0.f,l2a_y=0.f, ca_x=0.f,ca_y=0.f;
  float l2b_x=0.f,l2b_y=0.f, cb_x=0.f,cb_y=0.f;
  float ssq_x=0.f,ssq_y=0.f;
  float ssum_x=0.f,ssum_y=0.f, tsum_x=0.f,tsum_y=0.f;
  float smax_x=-INFINITY,smax_y=-INFINITY, tmax_x=-INFINITY,tmax_y=-INFINITY;

#pragma unroll 4
  for (int i = 0; i < 64; ++i) {
    const float2 sf = *(const float2*)(stu + idx);
    const float2 tf = *(const float2*)(tea + idx);
    const float2 o1 = *(const float2*)(o1p + idx);
    const float2 o2 = *(const float2*)(o2p + idx);
    const float2 sr = *(const float2*)(srp + idx);
    idx += HWPX;

    { float d = o1.x - o2.x; l2a_x += d * d;
      ca_x += (o1.x * o2.x) / fmaxf(fabsf(o1.x) * fabsf(o2.x), 1e-8f);
      float d2 = o1.x - sr.x; l2b_x += d2 * d2;
      cb_x += (o1.x * sr.x) / fmaxf(fabsf(o1.x) * fabsf(sr.x), 1e-8f);
      float ds = sf.x - tf.x; ssq_x += ds * ds;
      ssum_x += sf.x; tsum_x += tf.x;
      smax_x = fmaxf(smax_x, sf.x); tmax_x = fmaxf(tmax_x, tf.x); }
    { float d = o1.y - o2.y; l2a_y += d * d;
      ca_y += (o1.y * o2.y) / fmaxf(fabsf(o1.y) * fabsf(o2.y), 1e-8f);
      float d2 = o1.y - sr.y; l2b_y += d2 * d2;
      cb_y += (o1.y * sr.y) / fmaxf(fabsf(o1.y) * fabsf(sr.y), 1e-8f);
      float ds = sf.y - tf.y; ssq_y += ds * ds;
      ssum_y += sf.y; tsum_y += tf.y;
      smax_y = fmaxf(smax_y, sf.y); tmax_y = fmaxf(tmax_y, tf.y); }
  }

  // combine the 4 channel-chunks per pixel through LDS
  __shared__ float lds[4][128][9];
  {
    float* p = lds[chunk][lane * 2];
    p[0]=l2a_x; p[1]=ca_x; p[2]=l2b_x; p[3]=cb_x; p[4]=ssq_x;
    p[5]=ssum_x; p[6]=smax_x; p[7]=tsum_x; p[8]=tmax_x;
    float* q = lds[chunk][lane * 2 + 1];
    q[0]=l2a_y; q[1]=ca_y; q[2]=l2b_y; q[3]=cb_y; q[4]=ssq_y;
    q[5]=ssum_y; q[6]=smax_y; q[7]=tsum_y; q[8]=tmax_y;
  }
  __syncthreads();

  if (tid < 128) {  // waves 0-1: one lane per pixel; stride-9 reads are conflict-free
    float a0=0.f,a1=0.f,a2=0.f,a3=0.f,a4=0.f,a5=0.f,a7=0.f;
    float m6=-INFINITY, m8=-INFINITY;
#pragma unroll
    for (int k = 0; k < 4; ++k) {
      const float* q = lds[k][tid];
      a0+=q[0]; a1+=q[1]; a2+=q[2]; a3+=q[3]; a4+=q[4];
      a5+=q[5]; a7+=q[7];
      m6=fmaxf(m6,q[6]); m8=fmaxf(m8,q[8]);
    }
    const int gp = blockIdx.x * 128 + tid;
    const int bb = gp >> 12;
    const int pp = gp & 4095;

    float l2o = sqrtf(a0 + 1e-6f);
    float opt_d = (l2o + 1.0f - a1 * (1.0f / 256.0f)) * sigmoidf_(l2o * 5.0f);
    float l2h = sqrtf(a2 + 1e-6f);
    float het_d = (l2h + 1.0f - a3 * (1.0f / 256.0f)) * sigmoidf_(l2h * 5.0f);
    float ssp = sigmoidf_(a5 * (1.0f / 256.0f) + m6);
    float tsp = sigmoidf_(a7 * (1.0f / 256.0f) + m8);

    ws[OPTD_OFF + gp] = opt_d;
    ws[HETD_OFF + gp] = het_d;
    ws[SSP_OFF  + gp] = ssp;
    ws[TSP_OFF  + gp] = tsp;

    float mv = mkp[bb * HWPX + pp];
    float r0 = a4;            // sum (s-t)^2 over channels
    float r1 = mv * mv * a4;  // masked
    float r2 = opt_d;         // for mean(opt_diff)
    r0 = wred(r0); r1 = wred(r1); r2 = wred(r2);
    if ((tid & 63) == 0) {
      atomicAdd(&ws[ACC_OFF + 0], r0);
      atomicAdd(&ws[ACC_OFF + 1], r1);
      atomicAdd(&ws[ACC_OFF + 2], r2);
    }
  }
}

// ---------------- Kernel B: per-(b,c) channel sums (L3-hot re-read) ----------
// One wave per (b,c); 4096 pixels via 16 x float4 per tensor; single shuffle
// tree at the end; direct store (no atomics, no zeroing needed).
__global__ __launch_bounds__(256) void kernB(
    const float* __restrict__ stu, const float* __restrict__ tea,
    float* __restrict__ ws)
{
  const int wv   = (blockIdx.x * 256 + threadIdx.x) >> 6;  // global wave = bc index
  const int lane = threadIdx.x & 63;
  const size_t base = (size_t)wv * HWPX + lane * 4;
  float s = 0.f, t = 0.f;
#pragma unroll
  for (int i = 0; i < 16; ++i) {
    const float4 a = *(const float4*)(stu + base + i * 256);
    const float4 b = *(const float4*)(tea + base + i * 256);
    s += (a.x + a.y) + (a.z + a.w);
    t += (b.x + b.y) + (b.z + b.w);
  }
  s = wred(s); t = wred(t);
  if (lane == 0) {
    ws[SCHAN_OFF + wv] = s;
    ws[TCHAN_OFF + wv] = t;
  }
}

// ---------------- Kernel KL: 2-way softmax KL + class1 MSE -------------------
__global__ __launch_bounds__(256) void kernKL(
    const float* __restrict__ so, const float* __restrict__ to,
    float* __restrict__ ws)
{
  const int gid = blockIdx.x * 256 + threadIdx.x;  // 131072 threads, 4 px each
  const int p4 = gid << 2;
  const int b  = p4 >> 16;
  const int pp = p4 & 65535;
  const int i0 = b * 131072 + pp;

  const float4 s0 = *(const float4*)(so + i0);
  const float4 s1 = *(const float4*)(so + i0 + 65536);
  const float4 t0 = *(const float4*)(to + i0);
  const float4 t1 = *(const float4*)(to + i0 + 65536);

  float kl = 0.f, c1 = 0.f;
#define KLC(S0, S1, T0, T1)                                           \
  {                                                                   \
    float xs = (S1 - S0) * 0.25f;                                     \
    float xt = (T1 - T0) * 0.25f;                                     \
    float lzs = fmaxf(xs, 0.f) + log1pf(expf(-fabsf(xs)));            \
    float lzt = fmaxf(xt, 0.f) + log1pf(expf(-fabsf(xt)));            \
    float ls0 = -lzs, ls1 = xs - lzs;                                 \
    float lt0 = -lzt, lt1 = xt - lzt;                                 \
    float pt0 = expf(lt0), pt1 = expf(lt1);                           \
    kl += pt0 * (lt0 - ls0) + pt1 * (lt1 - ls1);                      \
    float ps1 = expf(ls1);                                            \
    float dd = ps1 - pt1;                                             \
    c1 += dd * dd;                                                    \
  }
  KLC(s0.x, s1.x, t0.x, t1.x)
  KLC(s0.y, s1.y, t0.y, t1.y)
  KLC(s0.z, s1.z, t0.z, t1.z)
  KLC(s0.w, s1.w, t0.w, t1.w)
#undef KLC

  kl = wred(kl);
  c1 = wred(c1);
  if ((threadIdx.x & 63) == 0) {
    atomicAdd(&ws[ACC_OFF + 3], kl);
    atomicAdd(&ws[ACC_OFF + 4], c1);
  }
}

// ---------------- Kernel C: mean-dependent terms -----------------------------
__global__ __launch_bounds__(256) void kernC(float* __restrict__ ws)
{
  const int gid = blockIdx.x * 256 + threadIdx.x;  // 0..32767
  float* acc = ws + ACC_OFF;
  const float mean_opt = acc[2] * (1.0f / 32768.0f);
  const float att_w = sigmoidf_(mean_opt * 10.0f);
  const float thr = mean_opt * 1.5f;

  const float od  = ws[OPTD_OFF + gid];
  const float hd  = ws[HETD_OFF + gid];
  const float ssp = ws[SSP_OFF + gid];
  const float tsp = ws[TSP_OFF + gid];
  const float mask = od > thr ? 1.0f : 0.0f;
  const float w = mask * 2.0f + (1.0f - mask) * 0.5f;
  float dt = (hd - od) * w; dt *= dt;
  const float amp = 1.0f + att_w * mask;
  float st = (ssp - tsp) * amp; st *= st;

  float cf = 0.f, catt = 0.f;
  if (gid < NCHAN) {
    const float sm = ws[SCHAN_OFF + gid] * (1.0f / 4096.0f);
    const float tm = ws[TCHAN_OFF + gid] * (1.0f / 4096.0f);
    const float d = sm - tm;
    cf = d * d;
    const float d2 = sigmoidf_(sm) - sigmoidf_(tm);
    catt = d2 * d2;
  }

  dt = wred(dt); st = wred(st); cf = wred(cf); catt = wred(catt);
  if ((threadIdx.x & 63) == 0) {
    atomicAdd(&acc[5], dt);
    atomicAdd(&acc[6], st);
    atomicAdd(&acc[7], cf);
    atomicAdd(&acc[8], catt);
  }
}

// ---------------- Kernel D: final scalar combine -----------------------------
__global__ void kernD(const float* __restrict__ ws, float* __restrict__ out)
{
  if (threadIdx.x != 0 || blockIdx.x != 0) return;
  const float* acc = ws + ACC_OFF;

  const float global_loss = acc[0] * (1.0f / (float)NFEAT);
  const float local_loss  = acc[1] * (1.0f / (float)NFEAT);
  const float chan_f      = acc[7] * (1.0f / (float)NCHAN);
  const float feat = 0.3f * global_loss + 0.5f * local_loss + 0.2f * chan_f;

  const float kl = acc[3] * (16.0f / 8.0f);           // * T^2 / B
  const float c1 = acc[4] * (2.0f / 524288.0f);       // mse * 2 over B*1*HO*HO
  const float outl = kl + c1;

  const float mean_opt = acc[2] * (1.0f / 32768.0f);
  const float att_w = sigmoidf_(mean_opt * 10.0f);
  const float diff_loss = acc[5] * (1.0f / 32768.0f);
  const float spat_loss = acc[6] * (1.0f / 32768.0f);
  const float chan_att  = acc[8] * (1.0f / (float)NCHAN);

  const float alpha = 0.5f * (1.0f + 0.5f * att_w);
  const float beta  = 0.3f * (1.0f - 0.3f * att_w);
  const float gamma = 0.2f * (1.0f + 0.5f * att_w);
  const float datt = alpha * diff_loss + beta * chan_att + gamma * spat_loss;

  const float total = 0.3f * feat + 0.4f * outl + 0.3f * datt;
  out[0] = total;
  out[1] = feat;
  out[2] = outl;
  out[3] = datt;
}

extern "C" void kernel_launch(void* const* d_in, const int* in_sizes, int n_in,
                              void* d_out, int out_size, void* d_ws, size_t ws_size,
                              hipStream_t stream)
{
  const float* stu = (const float*)d_in[0];
  const float* tea = (const float*)d_in[1];
  const float* so  = (const float*)d_in[2];
  const float* to  = (const float*)d_in[3];
  const float* o1  = (const float*)d_in[4];
  const float* o2  = (const float*)d_in[5];
  const float* sr  = (const float*)d_in[6];
  const float* mk  = (const float*)d_in[7];
  float* ws  = (float*)d_out ? (float*)d_ws : (float*)d_ws;
  float* out = (float*)d_out;

  // zero only the scalar accumulators (schan/tchan now written non-atomically)
  hipMemsetAsync(d_ws, 0, 16 * sizeof(float), stream);

  kernA<<<NPIX / 128, 256, 0, stream>>>(stu, tea, o1, o2, sr, mk, ws);
  kernB<<<NCHAN / 4, 256, 0, stream>>>(stu, tea, ws);
  kernKL<<<(524288 / 4) / 256, 256, 0, stream>>>(so, to, ws);
  kernC<<<NPIX / 256, 256, 0, stream>>>(ws);
  kernD<<<1, 64, 0, stream>>>(ws, out);
}

// Round 3
// 223.743 us; speedup vs baseline: 1.4111x; 1.3444x over previous
//
#include <hip/hip_runtime.h>
#include <math.h>

// Geometry: features [B=8,C=256,H=64,W=64]; outputs [8,2,256,256]
#define HWPX  4096
#define CCH   256
#define NPIX  32768
#define NCHAN 2048
#define NFEAT 8388608

// Workspace layout (floats). Scalar accumulators spread 128 B apart to avoid
// same-cacheline atomic serialization: ACC(i) = ws[i*32].
//  i: 0=ssq_global 1=ssq_local 2=sum_opt_diff 3=kl 4=class1
//     5=diff_sum 6=spatial_sum 7=chan_f 8=chan_att
#define PACC_OFF  512                 // 9 planes x NPIX per-pixel partials
#define ZERO_FLOATS (512 + 9 * NPIX) // memset region (accs + partials)
#define SCHAN_OFF 295424
#define TCHAN_OFF 297472
#define OPTD_OFF  299520
#define HETD_OFF  332288
#define SSP_OFF   365056
#define TSP_OFF   397824

__device__ __forceinline__ float sigmoidf_(float x) { return 1.0f / (1.0f + expf(-x)); }

__device__ __forceinline__ float wred(float v) {
#pragma unroll
  for (int o = 32; o > 0; o >>= 1) v += __shfl_down(v, o, 64);
  return v;
}

// monotone float<->uint mapping for atomicMax on floats (no NaNs in inputs)
__device__ __forceinline__ unsigned fmap(float x) {
  unsigned u = __float_as_uint(x);
  return (u & 0x80000000u) ? ~u : (u | 0x80000000u);
}
__device__ __forceinline__ float funmap(unsigned m) {
  return (m & 0x80000000u) ? __uint_as_float(m & 0x7FFFFFFFu) : __uint_as_float(~m);
}

// ---------------- Kernel A: streaming pass over the 5 big tensors ------------
// Grid 1024 blocks = 128 pixel-blocks x 8 channel-slices. Block: 4 waves, each
// wave owns 8 channels; lane owns 4 consecutive pixels (float4 = 1KiB/wave-ld).
// Epilogue: LDS combine (conflict-free b128 layout) -> per-pixel partial
// atomics into PACC (sums) / uint-mapped atomicMax (maxes).
__global__ __launch_bounds__(256, 4) void kernA(
    const float* __restrict__ stu, const float* __restrict__ tea,
    const float* __restrict__ o1p, const float* __restrict__ o2p,
    const float* __restrict__ srp, float* __restrict__ ws)
{
  const int tid  = threadIdx.x;
  const int lane = tid & 63;
  const int w    = tid >> 6;
  const int pb   = blockIdx.x >> 3;
  const int cbk  = blockIdx.x & 7;
  const int p0   = pb * 256 + lane * 4;
  const int b    = p0 >> 12;
  const int pin  = p0 & 4095;
  const int c0   = cbk * 32 + w * 8;
  size_t idx = ((size_t)(b * CCH + c0)) * HWPX + pin;

  const float4 Z = {0.f, 0.f, 0.f, 0.f};
  const float4 NI = {-INFINITY, -INFINITY, -INFINITY, -INFINITY};
  float4 l2a = Z, ca = Z, l2b = Z, cbn = Z, ssq = Z, ssm = Z, tsm = Z;
  float4 smx = NI, tmx = NI;

#pragma unroll 4
  for (int i = 0; i < 8; ++i) {
    const float4 sf = *(const float4*)(stu + idx);
    const float4 tf = *(const float4*)(tea + idx);
    const float4 o1 = *(const float4*)(o1p + idx);
    const float4 o2 = *(const float4*)(o2p + idx);
    const float4 sr = *(const float4*)(srp + idx);
    idx += HWPX;
#define UPD(K)                                                              \
    { float d = o1.K - o2.K; l2a.K += d * d;                                \
      ca.K  += (o1.K * o2.K) / fmaxf(fabsf(o1.K) * fabsf(o2.K), 1e-8f);     \
      float d2 = o1.K - sr.K; l2b.K += d2 * d2;                             \
      cbn.K += (o1.K * sr.K) / fmaxf(fabsf(o1.K) * fabsf(sr.K), 1e-8f);     \
      float ds = sf.K - tf.K; ssq.K += ds * ds;                             \
      ssm.K += sf.K; tsm.K += tf.K;                                         \
      smx.K = fmaxf(smx.K, sf.K); tmx.K = fmaxf(tmx.K, tf.K); }
    UPD(x) UPD(y) UPD(z) UPD(w)
#undef UPD
  }

  // LDS: [wave][quantity][pixel] -> b128 writes and stride-1 reads, conflict-free
  __shared__ float lds[4][9][256];
  *(float4*)&lds[w][0][lane * 4] = l2a;
  *(float4*)&lds[w][1][lane * 4] = ca;
  *(float4*)&lds[w][2][lane * 4] = l2b;
  *(float4*)&lds[w][3][lane * 4] = cbn;
  *(float4*)&lds[w][4][lane * 4] = ssq;
  *(float4*)&lds[w][5][lane * 4] = ssm;
  *(float4*)&lds[w][6][lane * 4] = smx;
  *(float4*)&lds[w][7][lane * 4] = tsm;
  *(float4*)&lds[w][8][lane * 4] = tmx;
  __syncthreads();

  // one thread per pixel: combine 4 waves, scatter to global partials
  float s0 = 0.f, s1 = 0.f, s2 = 0.f, s3 = 0.f, s4 = 0.f, s5 = 0.f, s7 = 0.f;
  float m6 = -INFINITY, m8 = -INFINITY;
#pragma unroll
  for (int k = 0; k < 4; ++k) {
    s0 += lds[k][0][tid]; s1 += lds[k][1][tid]; s2 += lds[k][2][tid];
    s3 += lds[k][3][tid]; s4 += lds[k][4][tid]; s5 += lds[k][5][tid];
    s7 += lds[k][7][tid];
    m6 = fmaxf(m6, lds[k][6][tid]);
    m8 = fmaxf(m8, lds[k][8][tid]);
  }
  const int gp = pb * 256 + tid;
  float* pa = ws + PACC_OFF;
  atomicAdd(&pa[0 * NPIX + gp], s0);
  atomicAdd(&pa[1 * NPIX + gp], s1);
  atomicAdd(&pa[2 * NPIX + gp], s2);
  atomicAdd(&pa[3 * NPIX + gp], s3);
  atomicAdd(&pa[4 * NPIX + gp], s4);
  atomicAdd(&pa[5 * NPIX + gp], s5);
  atomicAdd(&pa[7 * NPIX + gp], s7);
  atomicMax((unsigned*)&pa[6 * NPIX + gp], fmap(m6));
  atomicMax((unsigned*)&pa[8 * NPIX + gp], fmap(m8));
}

// ---------------- Kernel B: per-(b,c) channel sums ---------------------------
// One block per (b,c): 4 waves x 1024 px, float4; LDS combine; direct store.
__global__ __launch_bounds__(256) void kernB(
    const float* __restrict__ stu, const float* __restrict__ tea,
    float* __restrict__ ws)
{
  const int bc = blockIdx.x;
  const int tid = threadIdx.x, lane = tid & 63, w = tid >> 6;
  const size_t base = (size_t)bc * HWPX + w * 1024 + lane * 4;
  float s = 0.f, t = 0.f;
#pragma unroll
  for (int i = 0; i < 4; ++i) {
    const float4 a = *(const float4*)(stu + base + i * 256);
    const float4 b = *(const float4*)(tea + base + i * 256);
    s += (a.x + a.y) + (a.z + a.w);
    t += (b.x + b.y) + (b.z + b.w);
  }
  s = wred(s); t = wred(t);
  __shared__ float red[4][2];
  if (lane == 0) { red[w][0] = s; red[w][1] = t; }
  __syncthreads();
  if (tid == 0) {
    ws[SCHAN_OFF + bc] = red[0][0] + red[1][0] + red[2][0] + red[3][0];
    ws[TCHAN_OFF + bc] = red[0][1] + red[1][1] + red[2][1] + red[3][1];
  }
}

// ---------------- Kernel KL: 2-way softmax KL + class1 MSE -------------------
__global__ __launch_bounds__(256) void kernKL(
    const float* __restrict__ so, const float* __restrict__ to,
    float* __restrict__ ws)
{
  const int gid = blockIdx.x * 256 + threadIdx.x;
  const int p4 = gid << 2;
  const int b  = p4 >> 16;
  const int pp = p4 & 65535;
  const int i0 = b * 131072 + pp;

  const float4 s0 = *(const float4*)(so + i0);
  const float4 s1 = *(const float4*)(so + i0 + 65536);
  const float4 t0 = *(const float4*)(to + i0);
  const float4 t1 = *(const float4*)(to + i0 + 65536);

  float kl = 0.f, c1 = 0.f;
#define KLC(S0, S1, T0, T1)                                           \
  {                                                                   \
    float xs = (S1 - S0) * 0.25f;                                     \
    float xt = (T1 - T0) * 0.25f;                                     \
    float lzs = fmaxf(xs, 0.f) + log1pf(expf(-fabsf(xs)));            \
    float lzt = fmaxf(xt, 0.f) + log1pf(expf(-fabsf(xt)));            \
    float ls0 = -lzs, ls1 = xs - lzs;                                 \
    float lt0 = -lzt, lt1 = xt - lzt;                                 \
    float pt0 = expf(lt0), pt1 = expf(lt1);                           \
    kl += pt0 * (lt0 - ls0) + pt1 * (lt1 - ls1);                      \
    float ps1 = expf(ls1);                                            \
    float dd = ps1 - pt1;                                             \
    c1 += dd * dd;                                                    \
  }
  KLC(s0.x, s1.x, t0.x, t1.x)
  KLC(s0.y, s1.y, t0.y, t1.y)
  KLC(s0.z, s1.z, t0.z, t1.z)
  KLC(s0.w, s1.w, t0.w, t1.w)
#undef KLC

  kl = wred(kl);
  c1 = wred(c1);
  __shared__ float red[4][2];
  const int w = threadIdx.x >> 6;
  if ((threadIdx.x & 63) == 0) { red[w][0] = kl; red[w][1] = c1; }
  __syncthreads();
  if (threadIdx.x == 0) {
    atomicAdd(&ws[3 * 32], red[0][0] + red[1][0] + red[2][0] + red[3][0]);
    atomicAdd(&ws[4 * 32], red[0][1] + red[1][1] + red[2][1] + red[3][1]);
  }
}

// ---------------- Kernel C1: finalize per-pixel maps + global sums -----------
__global__ __launch_bounds__(256) void kernC1(
    const float* __restrict__ mk, float* __restrict__ ws)
{
  const int tid = threadIdx.x;
  const int gp = blockIdx.x * 256 + tid;
  const float* pa = ws + PACC_OFF;

  const float a0 = pa[0 * NPIX + gp];
  const float a1 = pa[1 * NPIX + gp];
  const float a2 = pa[2 * NPIX + gp];
  const float a3 = pa[3 * NPIX + gp];
  const float a4 = pa[4 * NPIX + gp];
  const float a5 = pa[5 * NPIX + gp];
  const float a7 = pa[7 * NPIX + gp];
  const float m6 = funmap(((const unsigned*)pa)[6 * NPIX + gp]);
  const float m8 = funmap(((const unsigned*)pa)[8 * NPIX + gp]);

  const float l2o = sqrtf(a0 + 1e-6f);
  const float opt_d = (l2o + 1.0f - a1 * (1.0f / 256.0f)) * sigmoidf_(l2o * 5.0f);
  const float l2h = sqrtf(a2 + 1e-6f);
  const float het_d = (l2h + 1.0f - a3 * (1.0f / 256.0f)) * sigmoidf_(l2h * 5.0f);
  const float ssp = sigmoidf_(a5 * (1.0f / 256.0f) + m6);
  const float tsp = sigmoidf_(a7 * (1.0f / 256.0f) + m8);

  ws[OPTD_OFF + gp] = opt_d;
  ws[HETD_OFF + gp] = het_d;
  ws[SSP_OFF  + gp] = ssp;
  ws[TSP_OFF  + gp] = tsp;

  const float mv = mk[gp];
  float r0 = a4, r1 = mv * mv * a4, r2 = opt_d;
  r0 = wred(r0); r1 = wred(r1); r2 = wred(r2);
  __shared__ float red[4][3];
  const int w = tid >> 6;
  if ((tid & 63) == 0) { red[w][0] = r0; red[w][1] = r1; red[w][2] = r2; }
  __syncthreads();
  if (tid == 0) {
    atomicAdd(&ws[0 * 32], red[0][0] + red[1][0] + red[2][0] + red[3][0]);
    atomicAdd(&ws[1 * 32], red[0][1] + red[1][1] + red[2][1] + red[3][1]);
    atomicAdd(&ws[2 * 32], red[0][2] + red[1][2] + red[2][2] + red[3][2]);
  }
}

// ---------------- Kernel C2: mean-dependent terms ----------------------------
__global__ __launch_bounds__(256) void kernC2(float* __restrict__ ws)
{
  const int tid = threadIdx.x;
  const int gid = blockIdx.x * 256 + tid;
  const float mean_opt = ws[2 * 32] * (1.0f / 32768.0f);
  const float att_w = sigmoidf_(mean_opt * 10.0f);
  const float thr = mean_opt * 1.5f;

  const float od  = ws[OPTD_OFF + gid];
  const float hd  = ws[HETD_OFF + gid];
  const float ssp = ws[SSP_OFF + gid];
  const float tsp = ws[TSP_OFF + gid];
  const float mask = od > thr ? 1.0f : 0.0f;
  const float wgt = mask * 2.0f + (1.0f - mask) * 0.5f;
  float dt = (hd - od) * wgt; dt *= dt;
  const float amp = 1.0f + att_w * mask;
  float st = (ssp - tsp) * amp; st *= st;

  float cf = 0.f, catt = 0.f;
  if (gid < NCHAN) {
    const float sm = ws[SCHAN_OFF + gid] * (1.0f / 4096.0f);
    const float tm = ws[TCHAN_OFF + gid] * (1.0f / 4096.0f);
    const float d = sm - tm;
    cf = d * d;
    const float d2 = sigmoidf_(sm) - sigmoidf_(tm);
    catt = d2 * d2;
  }

  dt = wred(dt); st = wred(st); cf = wred(cf); catt = wred(catt);
  __shared__ float red[4][4];
  const int w = tid >> 6;
  if ((tid & 63) == 0) { red[w][0] = dt; red[w][1] = st; red[w][2] = cf; red[w][3] = catt; }
  __syncthreads();
  if (tid == 0) {
    atomicAdd(&ws[5 * 32], red[0][0] + red[1][0] + red[2][0] + red[3][0]);
    atomicAdd(&ws[6 * 32], red[0][1] + red[1][1] + red[2][1] + red[3][1]);
    atomicAdd(&ws[7 * 32], red[0][2] + red[1][2] + red[2][2] + red[3][2]);
    atomicAdd(&ws[8 * 32], red[0][3] + red[1][3] + red[2][3] + red[3][3]);
  }
}

// ---------------- Kernel D: final scalar combine -----------------------------
__global__ void kernD(const float* __restrict__ ws, float* __restrict__ out)
{
  if (threadIdx.x != 0 || blockIdx.x != 0) return;

  const float global_loss = ws[0 * 32] * (1.0f / (float)NFEAT);
  const float local_loss  = ws[1 * 32] * (1.0f / (float)NFEAT);
  const float chan_f      = ws[7 * 32] * (1.0f / (float)NCHAN);
  const float feat = 0.3f * global_loss + 0.5f * local_loss + 0.2f * chan_f;

  const float kl = ws[3 * 32] * (16.0f / 8.0f);       // * T^2 / B
  const float c1 = ws[4 * 32] * (2.0f / 524288.0f);
  const float outl = kl + c1;

  const float mean_opt = ws[2 * 32] * (1.0f / 32768.0f);
  const float att_w = sigmoidf_(mean_opt * 10.0f);
  const float diff_loss = ws[5 * 32] * (1.0f / 32768.0f);
  const float spat_loss = ws[6 * 32] * (1.0f / 32768.0f);
  const float chan_att  = ws[8 * 32] * (1.0f / (float)NCHAN);

  const float alpha = 0.5f * (1.0f + 0.5f * att_w);
  const float beta  = 0.3f * (1.0f - 0.3f * att_w);
  const float gamma = 0.2f * (1.0f + 0.5f * att_w);
  const float datt = alpha * diff_loss + beta * chan_att + gamma * spat_loss;

  const float total = 0.3f * feat + 0.4f * outl + 0.3f * datt;
  out[0] = total;
  out[1] = feat;
  out[2] = outl;
  out[3] = datt;
}

extern "C" void kernel_launch(void* const* d_in, const int* in_sizes, int n_in,
                              void* d_out, int out_size, void* d_ws, size_t ws_size,
                              hipStream_t stream)
{
  const float* stu = (const float*)d_in[0];
  const float* tea = (const float*)d_in[1];
  const float* so  = (const float*)d_in[2];
  const float* to  = (const float*)d_in[3];
  const float* o1  = (const float*)d_in[4];
  const float* o2  = (const float*)d_in[5];
  const float* sr  = (const float*)d_in[6];
  const float* mk  = (const float*)d_in[7];
  float* ws  = (float*)d_ws;
  float* out = (float*)d_out;

  // zero acc scalars + per-pixel partial planes (1.18 MB)
  hipMemsetAsync(d_ws, 0, (size_t)ZERO_FLOATS * sizeof(float), stream);

  kernA<<<1024, 256, 0, stream>>>(stu, tea, o1, o2, sr, ws);
  kernB<<<2048, 256, 0, stream>>>(stu, tea, ws);
  kernKL<<<512, 256, 0, stream>>>(so, to, ws);
  kernC1<<<128, 256, 0, stream>>>(mk, ws);
  kernC2<<<128, 256, 0, stream>>>(ws);
  kernD<<<1, 64, 0, stream>>>(ws, out);
}

// Round 4
// 211.086 us; speedup vs baseline: 1.4957x; 1.0600x over previous
//
#include <hip/hip_runtime.h>
#include <math.h>

// Geometry: features [B=8,C=256,H=64,W=64]; outputs [8,2,256,256]
#define HWPX  4096
#define CCH   256
#define NPIX  32768
#define NCHAN 2048
#define NFEAT 8388608

// Workspace layout (floats). Every cell is written before it is read in the
// same launch sequence (no memset, no atomics anywhere).
#define A1P_OFF   0                         // 4 q x 8 slices x NPIX   (kernA1 partials)
#define A2P_OFF   (A1P_OFF + 4*8*NPIX)      // 5 q x 8 slices x NPIX   (kernA2 partials)
#define CHS_OFF   (A2P_OFF + 5*8*NPIX)      // 2048 bc x 16 pixel-block partial sums (student)
#define CHT_OFF   (CHS_OFF + NCHAN*16)      // teacher
#define OPTD_OFF  (CHT_OFF + NCHAN*16)      // 32768 per-pixel maps
#define HETD_OFF  (OPTD_OFF + NPIX)
#define SSP_OFF   (HETD_OFF + NPIX)
#define TSP_OFF   (SSP_OFF + NPIX)
#define KLP_OFF   (TSP_OFF + NPIX)          // 512 block partials (kernKL)
#define CL1_OFF   (KLP_OFF + 512)           // 512
#define GP0_OFF   (CL1_OFF + 512)           // 128 ssq_global partials (kernC1)
#define GP1_OFF   (GP0_OFF + 128)           // 128 ssq_local
#define GP2_OFF   (GP1_OFF + 128)           // 128 sum_opt_diff
#define DTP_OFF   (GP2_OFF + 128)           // 128 diff_loss partials (kernC2)
#define STP_OFF   (DTP_OFF + 128)           // 128 spatial
#define CFP_OFF   (STP_OFF + 128)           // 128 chan_f
#define CAP_OFF   (CFP_OFF + 128)           // 128 chan_att
// total ~2.56M floats = 10.3 MB

__device__ __forceinline__ float sigmoidf_(float x) { return 1.0f / (1.0f + expf(-x)); }

__device__ __forceinline__ float wred(float v) {
#pragma unroll
  for (int o = 32; o > 0; o >>= 1) v += __shfl_down(v, o, 64);
  return v;
}

// ---------- Kernel A1: opt_t1/opt_t2/sar_t2 (100 MB) -> diff-map partials ----
// Grid 1024 = 128 pixel-blocks x 8 channel-slices. Block: 256 px, 4 waves of
// 8 channels; lane owns 4 px (float4). Depth-2 explicit prefetch keeps ~9KB
// of loads in flight per wave (R3's 52-VGPR compile kept only ~3KB).
__global__ __launch_bounds__(256, 4) void kernA1(
    const float* __restrict__ o1p, const float* __restrict__ o2p,
    const float* __restrict__ srp, float* __restrict__ ws)
{
  const int tid = threadIdx.x, lane = tid & 63, w = tid >> 6;
  const int pb = blockIdx.x >> 3, cbk = blockIdx.x & 7;
  const int b = pb >> 4;
  const int pin = (pb & 15) * 256 + lane * 4;
  const int c0 = cbk * 32 + w * 8;
  size_t idx = ((size_t)(b * CCH + c0)) * HWPX + pin;

  float4 l2a = {0,0,0,0}, ca = {0,0,0,0}, l2b = {0,0,0,0}, cb = {0,0,0,0};

  float4 A0 = *(const float4*)(o1p + idx);
  float4 B0 = *(const float4*)(o2p + idx);
  float4 C0 = *(const float4*)(srp + idx);
  float4 A1 = *(const float4*)(o1p + idx + HWPX);
  float4 B1 = *(const float4*)(o2p + idx + HWPX);
  float4 C1 = *(const float4*)(srp + idx + HWPX);

#pragma unroll
  for (int i = 0; i < 8; ++i) {
    float4 A2 = A0, B2 = B0, C2 = C0;
    if (i < 6) {   // compile-time resolved (full unroll)
      A2 = *(const float4*)(o1p + idx + 2 * HWPX);
      B2 = *(const float4*)(o2p + idx + 2 * HWPX);
      C2 = *(const float4*)(srp + idx + 2 * HWPX);
    }
#define UPD1(K) { \
    float d = A0.K - B0.K; l2a.K = fmaf(d, d, l2a.K); \
    float p = A0.K * B0.K; \
    float den = fmaxf(fabsf(A0.K) * fabsf(B0.K), 1e-8f); \
    ca.K = fmaf(p, __builtin_amdgcn_rcpf(den), ca.K); \
    float d2 = A0.K - C0.K; l2b.K = fmaf(d2, d2, l2b.K); \
    float p2 = A0.K * C0.K; \
    float dn2 = fmaxf(fabsf(A0.K) * fabsf(C0.K), 1e-8f); \
    cb.K = fmaf(p2, __builtin_amdgcn_rcpf(dn2), cb.K); }
    UPD1(x) UPD1(y) UPD1(z) UPD1(w)
#undef UPD1
    A0 = A1; B0 = B1; C0 = C1;
    A1 = A2; B1 = B2; C1 = C2;
    idx += HWPX;
  }

  __shared__ float lds[4][4][256];   // 16 KB
  *(float4*)&lds[w][0][lane * 4] = l2a;
  *(float4*)&lds[w][1][lane * 4] = ca;
  *(float4*)&lds[w][2][lane * 4] = l2b;
  *(float4*)&lds[w][3][lane * 4] = cb;
  __syncthreads();

  float s0 = 0.f, s1 = 0.f, s2 = 0.f, s3 = 0.f;
#pragma unroll
  for (int k = 0; k < 4; ++k) {
    s0 += lds[k][0][tid]; s1 += lds[k][1][tid];
    s2 += lds[k][2][tid]; s3 += lds[k][3][tid];
  }
  const int gp = pb * 256 + tid;
  float* pa = ws + A1P_OFF;
  pa[(0 * 8 + cbk) * NPIX + gp] = s0;
  pa[(1 * 8 + cbk) * NPIX + gp] = s1;
  pa[(2 * 8 + cbk) * NPIX + gp] = s2;
  pa[(3 * 8 + cbk) * NPIX + gp] = s3;
}

// ---------- Kernel A2: student/teacher (67 MB) -> stat partials + chan sums --
// Same tiling as A1. Also produces per-(b,c) channel-sum partials (absorbs the
// old kernB 67 MB re-read); shuffle trees only in the epilogue.
__global__ __launch_bounds__(256, 4) void kernA2(
    const float* __restrict__ stu, const float* __restrict__ tea,
    float* __restrict__ ws)
{
  const int tid = threadIdx.x, lane = tid & 63, w = tid >> 6;
  const int pb = blockIdx.x >> 3, cbk = blockIdx.x & 7;
  const int b = pb >> 4;
  const int pin = (pb & 15) * 256 + lane * 4;
  const int c0 = cbk * 32 + w * 8;
  size_t idx = ((size_t)(b * CCH + c0)) * HWPX + pin;

  float4 ssq = {0,0,0,0}, ssm = {0,0,0,0}, tsm = {0,0,0,0};
  float4 smx = {-INFINITY,-INFINITY,-INFINITY,-INFINITY};
  float4 tmx = smx;
  float chS[8], chT[8];

  float4 S0 = *(const float4*)(stu + idx);
  float4 T0 = *(const float4*)(tea + idx);
  float4 S1 = *(const float4*)(stu + idx + HWPX);
  float4 T1 = *(const float4*)(tea + idx + HWPX);

#pragma unroll
  for (int i = 0; i < 8; ++i) {
    float4 S2 = S0, T2 = T0;
    if (i < 6) {
      S2 = *(const float4*)(stu + idx + 2 * HWPX);
      T2 = *(const float4*)(tea + idx + 2 * HWPX);
    }
#define UPD2(K) { \
    float ds = S0.K - T0.K; ssq.K = fmaf(ds, ds, ssq.K); \
    ssm.K += S0.K; tsm.K += T0.K; \
    smx.K = fmaxf(smx.K, S0.K); tmx.K = fmaxf(tmx.K, T0.K); }
    UPD2(x) UPD2(y) UPD2(z) UPD2(w)
#undef UPD2
    chS[i] = (S0.x + S0.y) + (S0.z + S0.w);
    chT[i] = (T0.x + T0.y) + (T0.z + T0.w);
    S0 = S1; T0 = T1;
    S1 = S2; T1 = T2;
    idx += HWPX;
  }

  __shared__ float lds[4][5][256];   // 20 KB
  *(float4*)&lds[w][0][lane * 4] = ssq;
  *(float4*)&lds[w][1][lane * 4] = ssm;
  *(float4*)&lds[w][2][lane * 4] = smx;
  *(float4*)&lds[w][3][lane * 4] = tsm;
  *(float4*)&lds[w][4][lane * 4] = tmx;
  __syncthreads();

  float s0 = 0.f, s1 = 0.f, s3 = 0.f;
  float m2 = -INFINITY, m4 = -INFINITY;
#pragma unroll
  for (int k = 0; k < 4; ++k) {
    s0 += lds[k][0][tid]; s1 += lds[k][1][tid]; s3 += lds[k][3][tid];
    m2 = fmaxf(m2, lds[k][2][tid]);
    m4 = fmaxf(m4, lds[k][4][tid]);
  }
  const int gp = pb * 256 + tid;
  float* pa = ws + A2P_OFF;
  pa[(0 * 8 + cbk) * NPIX + gp] = s0;  // ssq
  pa[(1 * 8 + cbk) * NPIX + gp] = s1;  // s_sum
  pa[(2 * 8 + cbk) * NPIX + gp] = m2;  // s_max
  pa[(3 * 8 + cbk) * NPIX + gp] = s3;  // t_sum
  pa[(4 * 8 + cbk) * NPIX + gp] = m4;  // t_max

  // per-(b,c) channel-sum partials: 16 shuffle trees, epilogue-only
#pragma unroll
  for (int i = 0; i < 8; ++i) {
    float cs = wred(chS[i]);
    float ct = wred(chT[i]);
    if (lane == 0) {
      const int bc = b * CCH + c0 + i;
      ws[CHS_OFF + bc * 16 + (pb & 15)] = cs;
      ws[CHT_OFF + bc * 16 + (pb & 15)] = ct;
    }
  }
}

// ---------- Kernel KL: 2-way softmax KL + class1 MSE (block partials) --------
__global__ __launch_bounds__(256) void kernKL(
    const float* __restrict__ so, const float* __restrict__ to,
    float* __restrict__ ws)
{
  const int gid = blockIdx.x * 256 + threadIdx.x;
  const int p4 = gid << 2;
  const int b  = p4 >> 16;
  const int pp = p4 & 65535;
  const int i0 = b * 131072 + pp;

  const float4 s0 = *(const float4*)(so + i0);
  const float4 s1 = *(const float4*)(so + i0 + 65536);
  const float4 t0 = *(const float4*)(to + i0);
  const float4 t1 = *(const float4*)(to + i0 + 65536);

  float kl = 0.f, c1 = 0.f;
#define KLC(S0, S1, T0, T1)                                           \
  {                                                                   \
    float xs = (S1 - S0) * 0.25f;                                     \
    float xt = (T1 - T0) * 0.25f;                                     \
    float lzs = fmaxf(xs, 0.f) + log1pf(expf(-fabsf(xs)));            \
    float lzt = fmaxf(xt, 0.f) + log1pf(expf(-fabsf(xt)));            \
    float ls0 = -lzs, ls1 = xs - lzs;                                 \
    float lt0 = -lzt, lt1 = xt - lzt;                                 \
    float pt0 = expf(lt0), pt1 = expf(lt1);                           \
    kl += pt0 * (lt0 - ls0) + pt1 * (lt1 - ls1);                      \
    float ps1 = expf(ls1);                                            \
    float dd = ps1 - pt1;                                             \
    c1 += dd * dd;                                                    \
  }
  KLC(s0.x, s1.x, t0.x, t1.x)
  KLC(s0.y, s1.y, t0.y, t1.y)
  KLC(s0.z, s1.z, t0.z, t1.z)
  KLC(s0.w, s1.w, t0.w, t1.w)
#undef KLC

  kl = wred(kl);
  c1 = wred(c1);
  __shared__ float red[4][2];
  const int w = threadIdx.x >> 6;
  if ((threadIdx.x & 63) == 0) { red[w][0] = kl; red[w][1] = c1; }
  __syncthreads();
  if (threadIdx.x == 0) {
    ws[KLP_OFF + blockIdx.x] = red[0][0] + red[1][0] + red[2][0] + red[3][0];
    ws[CL1_OFF + blockIdx.x] = red[0][1] + red[1][1] + red[2][1] + red[3][1];
  }
}

// ---------- Kernel C1: cross-slice combine, finalize maps, phase-1 sums ------
__global__ __launch_bounds__(256) void kernC1(
    const float* __restrict__ mk, float* __restrict__ ws)
{
  const int tid = threadIdx.x;
  const int gp = blockIdx.x * 256 + tid;
  const float* pA = ws + A1P_OFF;
  const float* pB = ws + A2P_OFF;

  float a0 = 0.f, a1 = 0.f, a2 = 0.f, a3 = 0.f;
  float b0 = 0.f, b1 = 0.f, b3 = 0.f;
  float m2 = -INFINITY, m4 = -INFINITY;
#pragma unroll
  for (int s = 0; s < 8; ++s) {
    a0 += pA[(0 * 8 + s) * NPIX + gp];
    a1 += pA[(1 * 8 + s) * NPIX + gp];
    a2 += pA[(2 * 8 + s) * NPIX + gp];
    a3 += pA[(3 * 8 + s) * NPIX + gp];
    b0 += pB[(0 * 8 + s) * NPIX + gp];
    b1 += pB[(1 * 8 + s) * NPIX + gp];
    m2 = fmaxf(m2, pB[(2 * 8 + s) * NPIX + gp]);
    b3 += pB[(3 * 8 + s) * NPIX + gp];
    m4 = fmaxf(m4, pB[(4 * 8 + s) * NPIX + gp]);
  }

  const float l2o = sqrtf(a0 + 1e-6f);
  const float opt_d = (l2o + 1.0f - a1 * (1.0f / 256.0f)) * sigmoidf_(l2o * 5.0f);
  const float l2h = sqrtf(a2 + 1e-6f);
  const float het_d = (l2h + 1.0f - a3 * (1.0f / 256.0f)) * sigmoidf_(l2h * 5.0f);
  const float ssp = sigmoidf_(b1 * (1.0f / 256.0f) + m2);
  const float tsp = sigmoidf_(b3 * (1.0f / 256.0f) + m4);

  ws[OPTD_OFF + gp] = opt_d;
  ws[HETD_OFF + gp] = het_d;
  ws[SSP_OFF  + gp] = ssp;
  ws[TSP_OFF  + gp] = tsp;

  const float mv = mk[gp];
  float r0 = b0, r1 = mv * mv * b0, r2 = opt_d;
  r0 = wred(r0); r1 = wred(r1); r2 = wred(r2);
  __shared__ float red[4][3];
  const int w = tid >> 6;
  if ((tid & 63) == 0) { red[w][0] = r0; red[w][1] = r1; red[w][2] = r2; }
  __syncthreads();
  if (tid == 0) {
    ws[GP0_OFF + blockIdx.x] = red[0][0] + red[1][0] + red[2][0] + red[3][0];
    ws[GP1_OFF + blockIdx.x] = red[0][1] + red[1][1] + red[2][1] + red[3][1];
    ws[GP2_OFF + blockIdx.x] = red[0][2] + red[1][2] + red[2][2] + red[3][2];
  }
}

// ---------- Kernel C2: mean-dependent terms + channel losses -----------------
__global__ __launch_bounds__(256) void kernC2(float* __restrict__ ws)
{
  const int tid = threadIdx.x;
  const int gid = blockIdx.x * 256 + tid;

  // every block re-derives sum(opt_diff) from the 128 C1 partials (cheap)
  float v = (tid < 128) ? ws[GP2_OFF + tid] : 0.f;
  v = wred(v);
  __shared__ float smo[4];
  if ((tid & 63) == 0) smo[tid >> 6] = v;
  __syncthreads();
  const float mean_opt = (smo[0] + smo[1] + smo[2] + smo[3]) * (1.0f / 32768.0f);
  const float att_w = sigmoidf_(mean_opt * 10.0f);
  const float thr = mean_opt * 1.5f;

  const float od  = ws[OPTD_OFF + gid];
  const float hd  = ws[HETD_OFF + gid];
  const float ssp = ws[SSP_OFF + gid];
  const float tsp = ws[TSP_OFF + gid];
  const float mask = od > thr ? 1.0f : 0.0f;
  const float wgt = mask * 2.0f + (1.0f - mask) * 0.5f;
  float dt = (hd - od) * wgt; dt *= dt;
  const float amp = 1.0f + att_w * mask;
  float st = (ssp - tsp) * amp; st *= st;

  float cf = 0.f, catt = 0.f;
  if (gid < NCHAN) {
    float s = 0.f, t = 0.f;
#pragma unroll
    for (int k = 0; k < 16; ++k) {
      s += ws[CHS_OFF + gid * 16 + k];
      t += ws[CHT_OFF + gid * 16 + k];
    }
    const float smn = s * (1.0f / 4096.0f);
    const float tmn = t * (1.0f / 4096.0f);
    const float d = smn - tmn;
    cf = d * d;
    const float d2 = sigmoidf_(smn) - sigmoidf_(tmn);
    catt = d2 * d2;
  }

  dt = wred(dt); st = wred(st); cf = wred(cf); catt = wred(catt);
  __shared__ float red[4][4];
  const int w = tid >> 6;
  if ((tid & 63) == 0) { red[w][0] = dt; red[w][1] = st; red[w][2] = cf; red[w][3] = catt; }
  __syncthreads();
  if (tid == 0) {
    ws[DTP_OFF + blockIdx.x] = red[0][0] + red[1][0] + red[2][0] + red[3][0];
    ws[STP_OFF + blockIdx.x] = red[0][1] + red[1][1] + red[2][1] + red[3][1];
    ws[CFP_OFF + blockIdx.x] = red[0][2] + red[1][2] + red[2][2] + red[3][2];
    ws[CAP_OFF + blockIdx.x] = red[0][3] + red[1][3] + red[2][3] + red[3][3];
  }
}

// ---------- Kernel D: final combine (single block, no atomics anywhere) ------
__global__ __launch_bounds__(256) void kernD(const float* __restrict__ ws,
                                             float* __restrict__ out)
{
  const int tid = threadIdx.x;
  __shared__ float sm[4];

  auto bsum = [&](int off, int n) -> float {
    float v = 0.f;
    for (int i = tid; i < n; i += 256) v += ws[off + i];
    v = wred(v);
    if ((tid & 63) == 0) sm[tid >> 6] = v;
    __syncthreads();
    const float r = sm[0] + sm[1] + sm[2] + sm[3];
    __syncthreads();
    return r;
  };

  const float ssqg = bsum(GP0_OFF, 128);
  const float ssql = bsum(GP1_OFF, 128);
  const float sopt = bsum(GP2_OFF, 128);
  const float kls  = bsum(KLP_OFF, 512);
  const float c1s  = bsum(CL1_OFF, 512);
  const float dts  = bsum(DTP_OFF, 128);
  const float sts  = bsum(STP_OFF, 128);
  const float cfs  = bsum(CFP_OFF, 128);
  const float cas  = bsum(CAP_OFF, 128);

  if (tid == 0) {
    const float global_loss = ssqg * (1.0f / (float)NFEAT);
    const float local_loss  = ssql * (1.0f / (float)NFEAT);
    const float chan_f      = cfs * (1.0f / (float)NCHAN);
    const float feat = 0.3f * global_loss + 0.5f * local_loss + 0.2f * chan_f;

    const float kl = kls * 2.0f;                 // * T^2 / B = 16/8
    const float c1 = c1s * (2.0f / 524288.0f);
    const float outl = kl + c1;

    const float mean_opt = sopt * (1.0f / 32768.0f);
    const float att_w = sigmoidf_(mean_opt * 10.0f);
    const float diff_loss = dts * (1.0f / 32768.0f);
    const float spat_loss = sts * (1.0f / 32768.0f);
    const float chan_att  = cas * (1.0f / (float)NCHAN);

    const float alpha = 0.5f * (1.0f + 0.5f * att_w);
    const float beta  = 0.3f * (1.0f - 0.3f * att_w);
    const float gamma = 0.2f * (1.0f + 0.5f * att_w);
    const float datt = alpha * diff_loss + beta * chan_att + gamma * spat_loss;

    const float total = 0.3f * feat + 0.4f * outl + 0.3f * datt;
    out[0] = total;
    out[1] = feat;
    out[2] = outl;
    out[3] = datt;
  }
}

extern "C" void kernel_launch(void* const* d_in, const int* in_sizes, int n_in,
                              void* d_out, int out_size, void* d_ws, size_t ws_size,
                              hipStream_t stream)
{
  const float* stu = (const float*)d_in[0];
  const float* tea = (const float*)d_in[1];
  const float* so  = (const float*)d_in[2];
  const float* to  = (const float*)d_in[3];
  const float* o1  = (const float*)d_in[4];
  const float* o2  = (const float*)d_in[5];
  const float* sr  = (const float*)d_in[6];
  const float* mk  = (const float*)d_in[7];
  float* ws  = (float*)d_ws;
  float* out = (float*)d_out;

  kernA1<<<1024, 256, 0, stream>>>(o1, o2, sr, ws);
  kernA2<<<1024, 256, 0, stream>>>(stu, tea, ws);
  kernKL<<<512, 256, 0, stream>>>(so, to, ws);
  kernC1<<<128, 256, 0, stream>>>(mk, ws);
  kernC2<<<128, 256, 0, stream>>>(ws);
  kernD<<<1, 256, 0, stream>>>(ws, out);
}

// Round 5
// 207.658 us; speedup vs baseline: 1.5204x; 1.0165x over previous
//
#include <hip/hip_runtime.h>
#include <math.h>

// Geometry: features [B=8,C=256,H=64,W=64]; outputs [8,2,256,256]
#define HWPX  4096
#define CCH   256
#define NPIX  32768
#define NCHAN 2048
#define NFEAT 8388608

// Workspace layout (floats). Every cell is written before it is read in the
// same launch sequence (no memset needed; harness poisons ws with 0xAA).
#define A1P_OFF   0                         // 4 q x 8 slices x NPIX   (A1 partials)
#define A2P_OFF   (A1P_OFF + 4*8*NPIX)      // 5 q x 8 slices x NPIX   (A2 partials)
#define CHS_OFF   (A2P_OFF + 5*8*NPIX)      // 2048 bc x 16 pixel-block partials (student)
#define CHT_OFF   (CHS_OFF + NCHAN*16)      // teacher
#define OPTD_OFF  (CHT_OFF + NCHAN*16)      // 32768 per-pixel maps
#define HETD_OFF  (OPTD_OFF + NPIX)
#define SSP_OFF   (HETD_OFF + NPIX)
#define TSP_OFF   (SSP_OFF + NPIX)
#define KLP_OFF   (TSP_OFF + NPIX)          // 512 block partials (KL)
#define CL1_OFF   (KLP_OFF + 512)           // 512
#define GP0_OFF   (CL1_OFF + 512)           // 128 ssq_global partials (kernC1)
#define GP1_OFF   (GP0_OFF + 128)           // 128 ssq_local
#define GP2_OFF   (GP1_OFF + 128)           // 128 sum_opt_diff
#define DTP_OFF   (GP2_OFF + 128)           // 128 diff_loss partials (kernC2D)
#define STP_OFF   (DTP_OFF + 128)           // 128 spatial
#define CFP_OFF   (STP_OFF + 128)           // 128 chan_f
#define CAP_OFF   (CFP_OFF + 128)           // 128 chan_att
#define CNT_OFF   (CAP_OFF + 128)           // 1 completion counter (zeroed by kernC1)

__device__ __forceinline__ float sigmoidf_(float x) { return 1.0f / (1.0f + expf(-x)); }

__device__ __forceinline__ float wred(float v) {
#pragma unroll
  for (int o = 32; o > 0; o >>= 1) v += __shfl_down(v, o, 64);
  return v;
}

// ---------- Kernel BIG: A1 | A2 | KL by block range --------------------------
// blocks [0,1024):    opt_t1/opt_t2/sar_t2 diff-map partials (100 MB)
// blocks [1024,2048): student/teacher stat partials + channel sums (67 MB)
// blocks [2048,2560): KL + class1 over outputs (8.4 MB)
__global__ __launch_bounds__(256, 4) void kernBIG(
    const float* __restrict__ o1p, const float* __restrict__ o2p,
    const float* __restrict__ srp,
    const float* __restrict__ stu, const float* __restrict__ tea,
    const float* __restrict__ so,  const float* __restrict__ to,
    float* __restrict__ ws)
{
  const int bid = blockIdx.x;
  const int tid = threadIdx.x, lane = tid & 63, w = tid >> 6;
  __shared__ float lds[4][5][256];   // 20 KB (A1 uses 4 planes, A2 uses 5)

  if (bid < 1024) {
    // ---------------- A1: diff maps ----------------
    const int pb = bid >> 3, cbk = bid & 7;
    const int b = pb >> 4;
    const int pin = (pb & 15) * 256 + lane * 4;
    const int c0 = cbk * 32 + w * 8;
    size_t idx = ((size_t)(b * CCH + c0)) * HWPX + pin;

    float4 l2a = {0,0,0,0}, ca = {0,0,0,0}, l2b = {0,0,0,0}, cb = {0,0,0,0};

    float4 A0 = *(const float4*)(o1p + idx);
    float4 B0 = *(const float4*)(o2p + idx);
    float4 C0 = *(const float4*)(srp + idx);
    float4 A1 = *(const float4*)(o1p + idx + HWPX);
    float4 B1 = *(const float4*)(o2p + idx + HWPX);
    float4 C1 = *(const float4*)(srp + idx + HWPX);

#pragma unroll
    for (int i = 0; i < 8; ++i) {
      float4 A2 = A0, B2 = B0, C2 = C0;
      if (i < 6) {
        A2 = *(const float4*)(o1p + idx + 2 * HWPX);
        B2 = *(const float4*)(o2p + idx + 2 * HWPX);
        C2 = *(const float4*)(srp + idx + 2 * HWPX);
      }
#define UPD1(K) { \
      float d = A0.K - B0.K; l2a.K = fmaf(d, d, l2a.K); \
      float p = A0.K * B0.K; \
      float den = fmaxf(fabsf(A0.K) * fabsf(B0.K), 1e-8f); \
      ca.K = fmaf(p, __builtin_amdgcn_rcpf(den), ca.K); \
      float d2 = A0.K - C0.K; l2b.K = fmaf(d2, d2, l2b.K); \
      float p2 = A0.K * C0.K; \
      float dn2 = fmaxf(fabsf(A0.K) * fabsf(C0.K), 1e-8f); \
      cb.K = fmaf(p2, __builtin_amdgcn_rcpf(dn2), cb.K); }
      UPD1(x) UPD1(y) UPD1(z) UPD1(w)
#undef UPD1
      A0 = A1; B0 = B1; C0 = C1;
      A1 = A2; B1 = B2; C1 = C2;
      idx += HWPX;
    }

    *(float4*)&lds[w][0][lane * 4] = l2a;
    *(float4*)&lds[w][1][lane * 4] = ca;
    *(float4*)&lds[w][2][lane * 4] = l2b;
    *(float4*)&lds[w][3][lane * 4] = cb;
    __syncthreads();

    float s0 = 0.f, s1 = 0.f, s2 = 0.f, s3 = 0.f;
#pragma unroll
    for (int k = 0; k < 4; ++k) {
      s0 += lds[k][0][tid]; s1 += lds[k][1][tid];
      s2 += lds[k][2][tid]; s3 += lds[k][3][tid];
    }
    const int gp = pb * 256 + tid;
    float* pa = ws + A1P_OFF;
    pa[(0 * 8 + cbk) * NPIX + gp] = s0;
    pa[(1 * 8 + cbk) * NPIX + gp] = s1;
    pa[(2 * 8 + cbk) * NPIX + gp] = s2;
    pa[(3 * 8 + cbk) * NPIX + gp] = s3;

  } else if (bid < 2048) {
    // ---------------- A2: student/teacher stats + channel sums ----------------
    const int bid2 = bid - 1024;
    const int pb = bid2 >> 3, cbk = bid2 & 7;
    const int b = pb >> 4;
    const int pin = (pb & 15) * 256 + lane * 4;
    const int c0 = cbk * 32 + w * 8;
    size_t idx = ((size_t)(b * CCH + c0)) * HWPX + pin;

    float4 ssq = {0,0,0,0}, ssm = {0,0,0,0}, tsm = {0,0,0,0};
    float4 smx = {-INFINITY,-INFINITY,-INFINITY,-INFINITY};
    float4 tmx = smx;
    float chS[8], chT[8];

    float4 S0 = *(const float4*)(stu + idx);
    float4 T0 = *(const float4*)(tea + idx);
    float4 S1 = *(const float4*)(stu + idx + HWPX);
    float4 T1 = *(const float4*)(tea + idx + HWPX);

#pragma unroll
    for (int i = 0; i < 8; ++i) {
      float4 S2 = S0, T2 = T0;
      if (i < 6) {
        S2 = *(const float4*)(stu + idx + 2 * HWPX);
        T2 = *(const float4*)(tea + idx + 2 * HWPX);
      }
#define UPD2(K) { \
      float ds = S0.K - T0.K; ssq.K = fmaf(ds, ds, ssq.K); \
      ssm.K += S0.K; tsm.K += T0.K; \
      smx.K = fmaxf(smx.K, S0.K); tmx.K = fmaxf(tmx.K, T0.K); }
      UPD2(x) UPD2(y) UPD2(z) UPD2(w)
#undef UPD2
      chS[i] = (S0.x + S0.y) + (S0.z + S0.w);
      chT[i] = (T0.x + T0.y) + (T0.z + T0.w);
      S0 = S1; T0 = T1;
      S1 = S2; T1 = T2;
      idx += HWPX;
    }

    *(float4*)&lds[w][0][lane * 4] = ssq;
    *(float4*)&lds[w][1][lane * 4] = ssm;
    *(float4*)&lds[w][2][lane * 4] = smx;
    *(float4*)&lds[w][3][lane * 4] = tsm;
    *(float4*)&lds[w][4][lane * 4] = tmx;
    __syncthreads();

    float s0 = 0.f, s1 = 0.f, s3 = 0.f;
    float m2 = -INFINITY, m4 = -INFINITY;
#pragma unroll
    for (int k = 0; k < 4; ++k) {
      s0 += lds[k][0][tid]; s1 += lds[k][1][tid]; s3 += lds[k][3][tid];
      m2 = fmaxf(m2, lds[k][2][tid]);
      m4 = fmaxf(m4, lds[k][4][tid]);
    }
    const int gp = pb * 256 + tid;
    float* pa = ws + A2P_OFF;
    pa[(0 * 8 + cbk) * NPIX + gp] = s0;  // ssq
    pa[(1 * 8 + cbk) * NPIX + gp] = s1;  // s_sum
    pa[(2 * 8 + cbk) * NPIX + gp] = m2;  // s_max
    pa[(3 * 8 + cbk) * NPIX + gp] = s3;  // t_sum
    pa[(4 * 8 + cbk) * NPIX + gp] = m4;  // t_max

#pragma unroll
    for (int i = 0; i < 8; ++i) {
      float cs = wred(chS[i]);
      float ct = wred(chT[i]);
      if (lane == 0) {
        const int bc = b * CCH + c0 + i;
        ws[CHS_OFF + bc * 16 + (pb & 15)] = cs;
        ws[CHT_OFF + bc * 16 + (pb & 15)] = ct;
      }
    }

  } else {
    // ---------------- KL: 2-way softmax KL + class1 MSE ----------------
    const int bkl = bid - 2048;                 // 0..511
    const int gid = bkl * 256 + tid;
    const int p4 = gid << 2;
    const int b  = p4 >> 16;
    const int pp = p4 & 65535;
    const int i0 = b * 131072 + pp;

    const float4 s0 = *(const float4*)(so + i0);
    const float4 s1 = *(const float4*)(so + i0 + 65536);
    const float4 t0 = *(const float4*)(to + i0);
    const float4 t1 = *(const float4*)(to + i0 + 65536);

    float kl = 0.f, c1 = 0.f;
#define KLC(S0, S1, T0, T1)                                           \
    {                                                                 \
      float xs = (S1 - S0) * 0.25f;                                   \
      float xt = (T1 - T0) * 0.25f;                                   \
      float lzs = fmaxf(xs, 0.f) + log1pf(expf(-fabsf(xs)));          \
      float lzt = fmaxf(xt, 0.f) + log1pf(expf(-fabsf(xt)));          \
      float ls0 = -lzs, ls1 = xs - lzs;                               \
      float lt0 = -lzt, lt1 = xt - lzt;                               \
      float pt0 = expf(lt0), pt1 = expf(lt1);                         \
      kl += pt0 * (lt0 - ls0) + pt1 * (lt1 - ls1);                    \
      float ps1 = expf(ls1);                                          \
      float dd = ps1 - pt1;                                           \
      c1 += dd * dd;                                                  \
    }
    KLC(s0.x, s1.x, t0.x, t1.x)
    KLC(s0.y, s1.y, t0.y, t1.y)
    KLC(s0.z, s1.z, t0.z, t1.z)
    KLC(s0.w, s1.w, t0.w, t1.w)
#undef KLC

    kl = wred(kl);
    c1 = wred(c1);
    if ((tid & 63) == 0) { lds[0][0][w * 2] = kl; lds[0][0][w * 2 + 1] = c1; }
    __syncthreads();
    if (tid == 0) {
      ws[KLP_OFF + bkl] = lds[0][0][0] + lds[0][0][2] + lds[0][0][4] + lds[0][0][6];
      ws[CL1_OFF + bkl] = lds[0][0][1] + lds[0][0][3] + lds[0][0][5] + lds[0][0][7];
    }
  }
}

// ---------- Kernel C1: cross-slice combine, finalize maps, phase-1 sums ------
__global__ __launch_bounds__(256) void kernC1(
    const float* __restrict__ mk, float* __restrict__ ws)
{
  const int tid = threadIdx.x;
  const int gp = blockIdx.x * 256 + tid;
  if (blockIdx.x == 0 && tid == 0) *(unsigned*)(ws + CNT_OFF) = 0u;  // arm C2D counter
  const float* pA = ws + A1P_OFF;
  const float* pB = ws + A2P_OFF;

  float a0 = 0.f, a1 = 0.f, a2 = 0.f, a3 = 0.f;
  float b0 = 0.f, b1 = 0.f, b3 = 0.f;
  float m2 = -INFINITY, m4 = -INFINITY;
#pragma unroll
  for (int s = 0; s < 8; ++s) {
    a0 += pA[(0 * 8 + s) * NPIX + gp];
    a1 += pA[(1 * 8 + s) * NPIX + gp];
    a2 += pA[(2 * 8 + s) * NPIX + gp];
    a3 += pA[(3 * 8 + s) * NPIX + gp];
    b0 += pB[(0 * 8 + s) * NPIX + gp];
    b1 += pB[(1 * 8 + s) * NPIX + gp];
    m2 = fmaxf(m2, pB[(2 * 8 + s) * NPIX + gp]);
    b3 += pB[(3 * 8 + s) * NPIX + gp];
    m4 = fmaxf(m4, pB[(4 * 8 + s) * NPIX + gp]);
  }

  const float l2o = sqrtf(a0 + 1e-6f);
  const float opt_d = (l2o + 1.0f - a1 * (1.0f / 256.0f)) * sigmoidf_(l2o * 5.0f);
  const float l2h = sqrtf(a2 + 1e-6f);
  const float het_d = (l2h + 1.0f - a3 * (1.0f / 256.0f)) * sigmoidf_(l2h * 5.0f);
  const float ssp = sigmoidf_(b1 * (1.0f / 256.0f) + m2);
  const float tsp = sigmoidf_(b3 * (1.0f / 256.0f) + m4);

  ws[OPTD_OFF + gp] = opt_d;
  ws[HETD_OFF + gp] = het_d;
  ws[SSP_OFF  + gp] = ssp;
  ws[TSP_OFF  + gp] = tsp;

  const float mv = mk[gp];
  float r0 = b0, r1 = mv * mv * b0, r2 = opt_d;
  r0 = wred(r0); r1 = wred(r1); r2 = wred(r2);
  __shared__ float red[4][3];
  const int w = tid >> 6;
  if ((tid & 63) == 0) { red[w][0] = r0; red[w][1] = r1; red[w][2] = r2; }
  __syncthreads();
  if (tid == 0) {
    ws[GP0_OFF + blockIdx.x] = red[0][0] + red[1][0] + red[2][0] + red[3][0];
    ws[GP1_OFF + blockIdx.x] = red[0][1] + red[1][1] + red[2][1] + red[3][1];
    ws[GP2_OFF + blockIdx.x] = red[0][2] + red[1][2] + red[2][2] + red[3][2];
  }
}

// ---------- Kernel C2D: mean-dependent terms + final combine (last block) ----
__global__ __launch_bounds__(256) void kernC2D(float* __restrict__ ws,
                                               float* __restrict__ out)
{
  const int tid = threadIdx.x;
  const int gid = blockIdx.x * 256 + tid;

  // re-derive sum(opt_diff) from the 128 C1 partials
  float v = (tid < 128) ? ws[GP2_OFF + tid] : 0.f;
  v = wred(v);
  __shared__ float smo[4];
  if ((tid & 63) == 0) smo[tid >> 6] = v;
  __syncthreads();
  const float mean_opt = (smo[0] + smo[1] + smo[2] + smo[3]) * (1.0f / 32768.0f);
  const float att_w = sigmoidf_(mean_opt * 10.0f);
  const float thr = mean_opt * 1.5f;

  const float od  = ws[OPTD_OFF + gid];
  const float hd  = ws[HETD_OFF + gid];
  const float ssp = ws[SSP_OFF + gid];
  const float tsp = ws[TSP_OFF + gid];
  const float mask = od > thr ? 1.0f : 0.0f;
  const float wgt = mask * 2.0f + (1.0f - mask) * 0.5f;
  float dt = (hd - od) * wgt; dt *= dt;
  const float amp = 1.0f + att_w * mask;
  float st = (ssp - tsp) * amp; st *= st;

  float cf = 0.f, catt = 0.f;
  if (gid < NCHAN) {
    float s = 0.f, t = 0.f;
#pragma unroll
    for (int k = 0; k < 16; ++k) {
      s += ws[CHS_OFF + gid * 16 + k];
      t += ws[CHT_OFF + gid * 16 + k];
    }
    const float smn = s * (1.0f / 4096.0f);
    const float tmn = t * (1.0f / 4096.0f);
    const float d = smn - tmn;
    cf = d * d;
    const float d2 = sigmoidf_(smn) - sigmoidf_(tmn);
    catt = d2 * d2;
  }

  dt = wred(dt); st = wred(st); cf = wred(cf); catt = wred(catt);
  __shared__ float red[4][4];
  const int w = tid >> 6;
  if ((tid & 63) == 0) { red[w][0] = dt; red[w][1] = st; red[w][2] = cf; red[w][3] = catt; }
  __syncthreads();
  if (tid == 0) {
    // agent-scope stores: bypass stale per-XCD L2 lines for intra-launch readers
    __hip_atomic_store(ws + DTP_OFF + blockIdx.x,
                       red[0][0] + red[1][0] + red[2][0] + red[3][0],
                       __ATOMIC_RELAXED, __HIP_MEMORY_SCOPE_AGENT);
    __hip_atomic_store(ws + STP_OFF + blockIdx.x,
                       red[0][1] + red[1][1] + red[2][1] + red[3][1],
                       __ATOMIC_RELAXED, __HIP_MEMORY_SCOPE_AGENT);
    __hip_atomic_store(ws + CFP_OFF + blockIdx.x,
                       red[0][2] + red[1][2] + red[2][2] + red[3][2],
                       __ATOMIC_RELAXED, __HIP_MEMORY_SCOPE_AGENT);
    __hip_atomic_store(ws + CAP_OFF + blockIdx.x,
                       red[0][3] + red[1][3] + red[2][3] + red[3][3],
                       __ATOMIC_RELAXED, __HIP_MEMORY_SCOPE_AGENT);
  }

  // ---- last block performs the final combine ----
  __shared__ bool isLast;
  if (tid == 0) {
    __threadfence();
    unsigned prev = __hip_atomic_fetch_add((unsigned*)(ws + CNT_OFF), 1u,
                                           __ATOMIC_ACQ_REL, __HIP_MEMORY_SCOPE_AGENT);
    isLast = (prev == 127u);
  }
  __syncthreads();
  if (!isLast) return;
  __threadfence();

  __shared__ float sm[4];
  auto bsum = [&](int off, int n) -> float {
    float acc = 0.f;
    for (int i = tid; i < n; i += 256)
      acc += __hip_atomic_load(ws + off + i, __ATOMIC_RELAXED, __HIP_MEMORY_SCOPE_AGENT);
    acc = wred(acc);
    if ((tid & 63) == 0) sm[tid >> 6] = acc;
    __syncthreads();
    const float r = sm[0] + sm[1] + sm[2] + sm[3];
    __syncthreads();
    return r;
  };

  const float ssqg = bsum(GP0_OFF, 128);
  const float ssql = bsum(GP1_OFF, 128);
  const float sopt = bsum(GP2_OFF, 128);
  const float kls  = bsum(KLP_OFF, 512);
  const float c1s  = bsum(CL1_OFF, 512);
  const float dts  = bsum(DTP_OFF, 128);
  const float sts  = bsum(STP_OFF, 128);
  const float cfs  = bsum(CFP_OFF, 128);
  const float cas  = bsum(CAP_OFF, 128);

  if (tid == 0) {
    const float global_loss = ssqg * (1.0f / (float)NFEAT);
    const float local_loss  = ssql * (1.0f / (float)NFEAT);
    const float chan_f      = cfs * (1.0f / (float)NCHAN);
    const float feat = 0.3f * global_loss + 0.5f * local_loss + 0.2f * chan_f;

    const float kl = kls * 2.0f;                 // * T^2 / B = 16/8
    const float c1 = c1s * (2.0f / 524288.0f);
    const float outl = kl + c1;

    const float mo = sopt * (1.0f / 32768.0f);
    const float aw = sigmoidf_(mo * 10.0f);
    const float diff_loss = dts * (1.0f / 32768.0f);
    const float spat_loss = sts * (1.0f / 32768.0f);
    const float chan_att  = cas * (1.0f / (float)NCHAN);

    const float alpha = 0.5f * (1.0f + 0.5f * aw);
    const float beta  = 0.3f * (1.0f - 0.3f * aw);
    const float gamma = 0.2f * (1.0f + 0.5f * aw);
    const float datt = alpha * diff_loss + beta * chan_att + gamma * spat_loss;

    const float total = 0.3f * feat + 0.4f * outl + 0.3f * datt;
    out[0] = total;
    out[1] = feat;
    out[2] = outl;
    out[3] = datt;
  }
}

extern "C" void kernel_launch(void* const* d_in, const int* in_sizes, int n_in,
                              void* d_out, int out_size, void* d_ws, size_t ws_size,
                              hipStream_t stream)
{
  const float* stu = (const float*)d_in[0];
  const float* tea = (const float*)d_in[1];
  const float* so  = (const float*)d_in[2];
  const float* to  = (const float*)d_in[3];
  const float* o1  = (const float*)d_in[4];
  const float* o2  = (const float*)d_in[5];
  const float* sr  = (const float*)d_in[6];
  const float* mk  = (const float*)d_in[7];
  float* ws  = (float*)d_ws;
  float* out = (float*)d_out;

  kernBIG<<<2560, 256, 0, stream>>>(o1, o2, sr, stu, tea, so, to, ws);
  kernC1<<<128, 256, 0, stream>>>(mk, ws);
  kernC2D<<<128, 256, 0, stream>>>(ws, out);
}